// Round 4
// baseline (119.727 us; speedup 1.0000x reference)
//
#include <hip/hip_runtime.h>
#include <hip/hip_bf16.h>
#include <stdint.h>

#define LEAKY_ALPHA 0.2f

using f32x4 = __attribute__((ext_vector_type(4))) float;
using u32x2 = __attribute__((ext_vector_type(2))) unsigned int;
using u32x4 = __attribute__((ext_vector_type(4))) unsigned int;
using i32x4 = __attribute__((ext_vector_type(4))) int;
using s16x8 = __attribute__((ext_vector_type(8))) short;

static __device__ __forceinline__ unsigned short f2bf(float x) {
  __hip_bfloat16 b = __float2bfloat16(x);
  return __builtin_bit_cast(unsigned short, b);
}

// ---------------------------------------------------------------------------
// Prep: WT[o][f] = bf16(W[f][o]);  wsum[f] = sum_o W[f][o]  (for exact fp32 s)
// ---------------------------------------------------------------------------
__global__ __launch_bounds__(256) void gat_prep(
    const float* __restrict__ W, __hip_bfloat16* __restrict__ WT,
    float* __restrict__ wsum)
{
  const int o = blockIdx.x;   // doubles as f-row index for wsum
  const int t = threadIdx.x;  // 256
  WT[o * 256 + t] = __float2bfloat16(W[t * 256 + o]);
  float u = W[o * 256 + t];
#pragma unroll
  for (int off = 1; off < 64; off <<= 1) u += __shfl_xor(u, off, 64);
  __shared__ float red[4];
  if ((t & 63) == 0) red[t >> 6] = u;
  __syncthreads();
  if (t == 0) wsum[o] = red[0] + red[1] + red[2] + red[3];
}

// ---------------------------------------------------------------------------
// Kernel A: WhT[b][o][q] = bf16( (h @ W)^T ) via MFMA; s[b][q] = h[q,:]·wsum
// (fp32 exact). Block = 64 q x 256 o, K=256 in 4 f-tiles. 256 blocks x 256 thr.
// ---------------------------------------------------------------------------
__global__ __launch_bounds__(256) void gat_wh2(
    const float* __restrict__ h, const __hip_bfloat16* __restrict__ WT,
    const float* __restrict__ wsum, __hip_bfloat16* __restrict__ WhT,
    float* __restrict__ s)
{
  const int b = blockIdx.x >> 5;
  const int q0 = (blockIdx.x & 31) * 64;
  const int t = threadIdx.x;
  const int wid = t >> 6, lane = t & 63;

  __shared__ __align__(16) unsigned char Bh[64 * 512];   // h bf16 [64q][256f] swz
  __shared__ __align__(16) unsigned char Aw[256 * 128];  // WT bf16 [256o][64f] swz
  __shared__ __align__(16) float wsl[256];

  wsl[t] = wsum[t];
  __syncthreads();

  // stage h -> Bh (bf16, swizzled) with fused fp32 s computation
  {
    const int q = t >> 2;
    const int fs = (t & 3) * 64;
    const float* hrow = h + ((size_t)(b * 2048 + q0 + q)) * 256 + fs;
    float sp = 0.f;
#pragma unroll
    for (int c = 0; c < 8; ++c) {
      const f32x4 a  = *(const f32x4*)&hrow[c * 8];
      const f32x4 bq = *(const f32x4*)&hrow[c * 8 + 4];
      const f32x4 wa = *(const f32x4*)&wsl[fs + c * 8];
      const f32x4 wb = *(const f32x4*)&wsl[fs + c * 8 + 4];
      sp += a[0]*wa[0] + a[1]*wa[1] + a[2]*wa[2] + a[3]*wa[3]
          + bq[0]*wb[0] + bq[1]*wb[1] + bq[2]*wb[2] + bq[3]*wb[3];
      u32x4 pk;
      pk[0] = (unsigned)f2bf(a[0])  | ((unsigned)f2bf(a[1])  << 16);
      pk[1] = (unsigned)f2bf(a[2])  | ((unsigned)f2bf(a[3])  << 16);
      pk[2] = (unsigned)f2bf(bq[0]) | ((unsigned)f2bf(bq[1]) << 16);
      pk[3] = (unsigned)f2bf(bq[2]) | ((unsigned)f2bf(bq[3]) << 16);
      const int boff = q * 512 + ((fs * 2 + c * 16) ^ ((q & 7) << 4));
      *(u32x4*)&Bh[boff] = pk;
    }
    sp += __shfl_xor(sp, 1, 64);
    sp += __shfl_xor(sp, 2, 64);
    if ((t & 3) == 0) s[b * 2048 + q0 + q] = sp;
  }

  f32x4 acc[4][4];
#pragma unroll
  for (int i = 0; i < 4; ++i)
#pragma unroll
    for (int j = 0; j < 4; ++j) acc[i][j] = (f32x4)(0.f);

  for (int it = 0; it < 4; ++it) {
    const int f0 = it * 64;
    __syncthreads();   // it=0: Bh visible; it>0: protect Aw from prev reads
#pragma unroll
    for (int j = 0; j < 8; ++j) {
      const int o = (t >> 3) + 32 * j;
      const int c = t & 7;
      const u32x4 v = *(const u32x4*)&WT[o * 256 + f0 + c * 8];
      *(u32x4*)&Aw[o * 128 + ((c * 16) ^ ((o & 7) << 4))] = v;
    }
    __syncthreads();
#pragma unroll
    for (int kt = 0; kt < 2; ++kt) {
      const int kb = kt * 64 + ((lane >> 4) << 4);   // byte off within 64-f span
      s16x8 af[4], bf[4];
#pragma unroll
      for (int qt = 0; qt < 4; ++qt) {
        const int qr = qt * 16 + (lane & 15);
        af[qt] = *(const s16x8*)&Bh[qr * 512 + ((f0 * 2 + kb) ^ ((qr & 7) << 4))];
      }
#pragma unroll
      for (int ot = 0; ot < 4; ++ot) {
        const int orow = wid * 64 + ot * 16 + (lane & 15);
        bf[ot] = *(const s16x8*)&Aw[orow * 128 + (kb ^ ((orow & 7) << 4))];
      }
#pragma unroll
      for (int qt = 0; qt < 4; ++qt)
#pragma unroll
        for (int ot = 0; ot < 4; ++ot)
          acc[qt][ot] = __builtin_amdgcn_mfma_f32_16x16x32_bf16(
              af[qt], bf[ot], acc[qt][ot], 0, 0, 0);
    }
  }

  // epilogue: WhT[b][o][q0+q]; C-row = q (r contiguous) -> 8B vector stores
  __hip_bfloat16* __restrict__ WhTb = WhT + (size_t)b * 256 * 2048;
#pragma unroll
  for (int qt = 0; qt < 4; ++qt)
#pragma unroll
    for (int ot = 0; ot < 4; ++ot) {
      const int o = wid * 64 + ot * 16 + (lane & 15);
      const int ql = q0 + qt * 16 + ((lane >> 4) << 2);
      u32x2 pk;
      pk[0] = (unsigned)f2bf(acc[qt][ot][0]) | ((unsigned)f2bf(acc[qt][ot][1]) << 16);
      pk[1] = (unsigned)f2bf(acc[qt][ot][2]) | ((unsigned)f2bf(acc[qt][ot][3]) << 16);
      *(u32x2*)&WhTb[(size_t)o * 2048 + ql] = pk;
    }
}

// ---------------------------------------------------------------------------
// Kernel B: fused masked-softmax + PV. Fixed per-row bound m_p (no rescale).
// q-step 128. P tile (32x128 bf16) in dbuf LDS, one lgkm-drain barrier/tile.
// B-fragments loaded global->VGPR directly (no LDS stage), issued one tile
// ahead, in flight across exactly one barrier.
// ---------------------------------------------------------------------------
struct GatTile {
  i32x4 a0, a1;    // adj[8]
  f32x4 s0, s1;    // s[8]
  u32x4 bv[8];     // B fragments: [ot*4+kt], 16B each
};

__global__ __launch_bounds__(512, 4) void gat_attn(
    const int* __restrict__ adj, const float* __restrict__ s,
    const __hip_bfloat16* __restrict__ WhT, float* __restrict__ out)
{
  const int N = 2048;
  const int bid = blockIdx.x;
  const int swz = (bid & 7) * 64 + (bid >> 3);   // XCD-major: batch == XCD
  const int b = swz >> 6;
  const int p0 = (swz & 63) * 32;
  const int t = threadIdx.x;
  const int wid = t >> 6, lane = t & 63;

  __shared__ __align__(16) unsigned char Wt[2][32 * 256]; // P tile [32p][128q] dbuf
  __shared__ __align__(16) float red_sh[8];
  __shared__ __align__(16) float l_sh[32];

  const int ep = t >> 4;              // p-row 0..31 (16 thr/row)
  const int eq = (t & 15) * 8;        // 8 q per thread
  const int* __restrict__ adjrow = adj + ((size_t)(b * N + p0 + ep)) * N;
  const float* __restrict__ sB = s + b * N;
  const __hip_bfloat16* __restrict__ WhTb = WhT + (size_t)b * 256 * 2048;
  // per-lane B base: row o = wid*32 + (lane&15), q-chunk (lane>>4)*8
  const __hip_bfloat16* __restrict__ bbase =
      WhTb + (size_t)(wid * 32 + (lane & 15)) * 2048 + ((lane >> 4) << 3);
  const int wchunk = (t & 15) ^ (ep & 15);       // swizzled write chunk

  // ---- block-wide smax over s[b,:] (fixed softmax bound) ----
  const f32x4 s4 = *(const f32x4*)&sB[t * 4];
  float bm = fmaxf(fmaxf(s4[0], s4[1]), fmaxf(s4[2], s4[3]));
#pragma unroll
  for (int off = 1; off < 64; off <<= 1) bm = fmaxf(bm, __shfl_xor(bm, off, 64));
  if (lane == 0) red_sh[wid] = bm;
  const float s_p = sB[p0 + ep];
  __syncthreads();
  float smax = red_sh[0];
#pragma unroll
  for (int k = 1; k < 8; ++k) smax = fmaxf(smax, red_sh[k]);
  const float xm = s_p + smax;
  const float m_p = (xm > 0.f) ? xm : (LEAKY_ALPHA * xm);

  f32x4 acc[2][2];
#pragma unroll
  for (int pt = 0; pt < 2; ++pt)
#pragma unroll
    for (int ot = 0; ot < 2; ++ot) acc[pt][ot] = (f32x4)(0.f);
  float lacc = 0.f;

  GatTile TA, TB;
  // ---- prologue: tile 0 into TA ----
  TA.a0 = *(const i32x4*)&adjrow[eq];
  TA.a1 = *(const i32x4*)&adjrow[eq + 4];
  TA.s0 = *(const f32x4*)&sB[eq];
  TA.s1 = *(const f32x4*)&sB[eq + 4];
#pragma unroll
  for (int ot = 0; ot < 2; ++ot)
#pragma unroll
    for (int kt = 0; kt < 4; ++kt)
      TA.bv[ot * 4 + kt] = *(const u32x4*)&bbase[ot * 16 * 2048 + kt * 32];

#define GAT_TILE(BI, QQ, CUR, NXT)                                            \
  do {                                                                        \
    /* scores: 8 q per thread */                                              \
    float wv[8];                                                              \
    const float sq[8] = {CUR.s0[0], CUR.s0[1], CUR.s0[2], CUR.s0[3],          \
                         CUR.s1[0], CUR.s1[1], CUR.s1[2], CUR.s1[3]};         \
    const int avm[8] = {CUR.a0[0], CUR.a0[1], CUR.a0[2], CUR.a0[3],           \
                        CUR.a1[0], CUR.a1[1], CUR.a1[2], CUR.a1[3]};          \
    _Pragma("unroll")                                                         \
    for (int i = 0; i < 8; ++i) {                                             \
      const float x = s_p + sq[i];                                            \
      const float le = (x > 0.f) ? x : (LEAKY_ALPHA * x);                     \
      const float w = __expf(le - m_p);                                       \
      wv[i] = (avm[i] != 0) ? w : 0.f;                                        \
      lacc += wv[i];                                                          \
    }                                                                         \
    {                                                                         \
      u32x4 pw;                                                               \
      _Pragma("unroll")                                                       \
      for (int k2 = 0; k2 < 4; ++k2)                                          \
        pw[k2] = (unsigned)f2bf(wv[2 * k2]) |                                 \
                 ((unsigned)f2bf(wv[2 * k2 + 1]) << 16);                      \
      *(u32x4*)&Wt[BI][ep * 256 + wchunk * 16] = pw;                          \
    }                                                                         \
    /* prefetch next tile's adj/s */                                          \
    if ((QQ) + 128 < N) {                                                     \
      NXT.a0 = *(const i32x4*)&adjrow[(QQ) + 128 + eq];                       \
      NXT.a1 = *(const i32x4*)&adjrow[(QQ) + 128 + eq + 4];                   \
      NXT.s0 = *(const f32x4*)&sB[(QQ) + 128 + eq];                           \
      NXT.s1 = *(const f32x4*)&sB[(QQ) + 128 + eq + 4];                       \
    }                                                                         \
    asm volatile("s_waitcnt lgkmcnt(0)" ::: "memory");                        \
    __builtin_amdgcn_s_barrier();                                             \
    asm volatile("" ::: "memory");                                            \
    {                                                                         \
      s16x8 afr[2][4];                                                        \
      _Pragma("unroll")                                                       \
      for (int pt = 0; pt < 2; ++pt)                                          \
        _Pragma("unroll")                                                     \
        for (int kt = 0; kt < 4; ++kt) {                                      \
          const int pa = pt * 16 + (lane & 15);                               \
          const int ck = (kt * 4 + (lane >> 4)) ^ (pa & 15);                  \
          afr[pt][kt] = *(const s16x8*)&Wt[BI][pa * 256 + ck * 16];           \
        }                                                                     \
      __builtin_amdgcn_s_setprio(1);                                          \
      _Pragma("unroll")                                                       \
      for (int pt = 0; pt < 2; ++pt)                                          \
        _Pragma("unroll")                                                     \
        for (int ot = 0; ot < 2; ++ot)                                        \
          _Pragma("unroll")                                                   \
          for (int kt = 0; kt < 4; ++kt)                                      \
            acc[pt][ot] = __builtin_amdgcn_mfma_f32_16x16x32_bf16(            \
                afr[pt][kt], __builtin_bit_cast(s16x8, CUR.bv[ot * 4 + kt]),  \
                acc[pt][ot], 0, 0, 0);                                        \
      __builtin_amdgcn_s_setprio(0);                                          \
    }                                                                         \
    /* issue next tile's B fragments (in flight across next barrier) */       \
    if ((QQ) + 128 < N) {                                                     \
      _Pragma("unroll")                                                       \
      for (int ot = 0; ot < 2; ++ot)                                          \
        _Pragma("unroll")                                                     \
        for (int kt = 0; kt < 4; ++kt)                                        \
          NXT.bv[ot * 4 + kt] =                                               \
              *(const u32x4*)&bbase[ot * 16 * 2048 + (QQ) + 128 + kt * 32];   \
    }                                                                         \
  } while (0)

  for (int q0 = 0; q0 < N; q0 += 256) {
    GAT_TILE(0, q0, TA, TB);
    GAT_TILE(1, q0 + 128, TB, TA);
  }
#undef GAT_TILE

  // ---- l reduction: 16 threads per row -> l_sh ----
  lacc += __shfl_xor(lacc, 1, 64);
  lacc += __shfl_xor(lacc, 2, 64);
  lacc += __shfl_xor(lacc, 4, 64);
  lacc += __shfl_xor(lacc, 8, 64);
  if ((t & 15) == 0) l_sh[ep] = lacc;
  __syncthreads();

  // ---- epilogue: divide by l, store fp32 ----
#pragma unroll
  for (int pt = 0; pt < 2; ++pt) {
    const f32x4 lv = *(const f32x4*)&l_sh[pt * 16 + ((lane >> 4) << 2)];
    f32x4 inv;
#pragma unroll
    for (int r = 0; r < 4; ++r) inv[r] = 1.f / lv[r];
#pragma unroll
    for (int ot = 0; ot < 2; ++ot) {
      const int o = wid * 32 + ot * 16 + (lane & 15);
#pragma unroll
      for (int r = 0; r < 4; ++r) {
        const int row = p0 + pt * 16 + ((lane >> 4) << 2) + r;
        out[((size_t)(b * N + row)) * 256 + o] = acc[pt][ot][r] * inv[r];
      }
    }
  }
}

extern "C" void kernel_launch(void* const* d_in, const int* in_sizes, int n_in,
                              void* d_out, int out_size, void* d_ws, size_t ws_size,
                              hipStream_t stream) {
  const float* h = (const float*)d_in[0];
  const int* adj = (const int*)d_in[1];
  const float* W = (const float*)d_in[2];
  float* out = (float*)d_out;

  char* ws = (char*)d_ws;
  __hip_bfloat16* WhT = (__hip_bfloat16*)ws;                              // 8 MiB
  float* s = (float*)(ws + (size_t)8 * 1024 * 1024);                      // 64 KiB
  __hip_bfloat16* WT = (__hip_bfloat16*)(ws + (size_t)8 * 1024 * 1024 + 65536);   // 128 KiB
  float* wsum = (float*)(ws + (size_t)8 * 1024 * 1024 + 65536 + 131072);  // 1 KiB

  gat_prep<<<256, 256, 0, stream>>>(W, WT, wsum);
  gat_wh2<<<256, 256, 0, stream>>>(h, WT, wsum, WhT, s);
  gat_attn<<<512, 512, 0, stream>>>(adj, s, WhT, out);
}

// Round 5
// 57.845 us; speedup vs baseline: 2.0698x; 2.0698x over previous
//
#include <hip/hip_runtime.h>
#include <hip/hip_bf16.h>
#include <stdint.h>

#define LEAKY_ALPHA 0.2f

using f32x4 = __attribute__((ext_vector_type(4))) float;
using u32x2 = __attribute__((ext_vector_type(2))) unsigned int;
using u32x4 = __attribute__((ext_vector_type(4))) unsigned int;
using i32x4 = __attribute__((ext_vector_type(4))) int;
using s16x8 = __attribute__((ext_vector_type(8))) short;

static __device__ __forceinline__ unsigned short f2bf(float x) {
  __hip_bfloat16 b = __float2bfloat16(x);
  return __builtin_bit_cast(unsigned short, b);
}

// ---------------------------------------------------------------------------
// Prep: WT[o][f] = bf16(W[f][o]);  wsum[f] = sum_o W[f][o]  (for exact fp32 s)
// ---------------------------------------------------------------------------
__global__ __launch_bounds__(256) void gat_prep(
    const float* __restrict__ W, __hip_bfloat16* __restrict__ WT,
    float* __restrict__ wsum)
{
  const int o = blockIdx.x;   // doubles as f-row index for wsum
  const int t = threadIdx.x;  // 256
  WT[o * 256 + t] = __float2bfloat16(W[t * 256 + o]);
  float u = W[o * 256 + t];
#pragma unroll
  for (int off = 1; off < 64; off <<= 1) u += __shfl_xor(u, off, 64);
  __shared__ float red[4];
  if ((t & 63) == 0) red[t >> 6] = u;
  __syncthreads();
  if (t == 0) wsum[o] = red[0] + red[1] + red[2] + red[3];
}

// ---------------------------------------------------------------------------
// Kernel A: WhT[b][o][q] = bf16( (h @ W)^T ) via MFMA; s[b][q] = h[q,:]·wsum
// (fp32 exact). Block = 64 q x 256 o, K=256 in 4 f-tiles. 256 blocks x 256 thr.
// ---------------------------------------------------------------------------
__global__ __launch_bounds__(256) void gat_wh2(
    const float* __restrict__ h, const __hip_bfloat16* __restrict__ WT,
    const float* __restrict__ wsum, __hip_bfloat16* __restrict__ WhT,
    float* __restrict__ s)
{
  const int b = blockIdx.x >> 5;
  const int q0 = (blockIdx.x & 31) * 64;
  const int t = threadIdx.x;
  const int wid = t >> 6, lane = t & 63;

  __shared__ __align__(16) unsigned char Bh[64 * 512];   // h bf16 [64q][256f] swz
  __shared__ __align__(16) unsigned char Aw[256 * 128];  // WT bf16 [256o][64f] swz
  __shared__ __align__(16) float wsl[256];

  wsl[t] = wsum[t];
  __syncthreads();

  // stage h -> Bh (bf16, swizzled) with fused fp32 s computation
  {
    const int q = t >> 2;
    const int fs = (t & 3) * 64;
    const float* hrow = h + ((size_t)(b * 2048 + q0 + q)) * 256 + fs;
    float sp = 0.f;
#pragma unroll
    for (int c = 0; c < 8; ++c) {
      const f32x4 a  = *(const f32x4*)&hrow[c * 8];
      const f32x4 bq = *(const f32x4*)&hrow[c * 8 + 4];
      const f32x4 wa = *(const f32x4*)&wsl[fs + c * 8];
      const f32x4 wb = *(const f32x4*)&wsl[fs + c * 8 + 4];
      sp += a[0]*wa[0] + a[1]*wa[1] + a[2]*wa[2] + a[3]*wa[3]
          + bq[0]*wb[0] + bq[1]*wb[1] + bq[2]*wb[2] + bq[3]*wb[3];
      u32x4 pk;
      pk[0] = (unsigned)f2bf(a[0])  | ((unsigned)f2bf(a[1])  << 16);
      pk[1] = (unsigned)f2bf(a[2])  | ((unsigned)f2bf(a[3])  << 16);
      pk[2] = (unsigned)f2bf(bq[0]) | ((unsigned)f2bf(bq[1]) << 16);
      pk[3] = (unsigned)f2bf(bq[2]) | ((unsigned)f2bf(bq[3]) << 16);
      const int boff = q * 512 + ((fs * 2 + c * 16) ^ ((q & 7) << 4));
      *(u32x4*)&Bh[boff] = pk;
    }
    sp += __shfl_xor(sp, 1, 64);
    sp += __shfl_xor(sp, 2, 64);
    if ((t & 3) == 0) s[b * 2048 + q0 + q] = sp;
  }

  f32x4 acc[4][4];
#pragma unroll
  for (int i = 0; i < 4; ++i)
#pragma unroll
    for (int j = 0; j < 4; ++j) acc[i][j] = (f32x4)(0.f);

  for (int it = 0; it < 4; ++it) {
    const int f0 = it * 64;
    __syncthreads();   // it=0: Bh visible; it>0: protect Aw from prev reads
#pragma unroll
    for (int j = 0; j < 8; ++j) {
      const int o = (t >> 3) + 32 * j;
      const int c = t & 7;
      const u32x4 v = *(const u32x4*)&WT[o * 256 + f0 + c * 8];
      *(u32x4*)&Aw[o * 128 + ((c * 16) ^ ((o & 7) << 4))] = v;
    }
    __syncthreads();
#pragma unroll
    for (int kt = 0; kt < 2; ++kt) {
      const int kb = kt * 64 + ((lane >> 4) << 4);   // byte off within 64-f span
      s16x8 af[4], bf[4];
#pragma unroll
      for (int qt = 0; qt < 4; ++qt) {
        const int qr = qt * 16 + (lane & 15);
        af[qt] = *(const s16x8*)&Bh[qr * 512 + ((f0 * 2 + kb) ^ ((qr & 7) << 4))];
      }
#pragma unroll
      for (int ot = 0; ot < 4; ++ot) {
        const int orow = wid * 64 + ot * 16 + (lane & 15);
        bf[ot] = *(const s16x8*)&Aw[orow * 128 + (kb ^ ((orow & 7) << 4))];
      }
#pragma unroll
      for (int qt = 0; qt < 4; ++qt)
#pragma unroll
        for (int ot = 0; ot < 4; ++ot)
          acc[qt][ot] = __builtin_amdgcn_mfma_f32_16x16x32_bf16(
              af[qt], bf[ot], acc[qt][ot], 0, 0, 0);
    }
  }

  // epilogue: WhT[b][o][q0+q]; C-row = q (r contiguous) -> 8B vector stores
  __hip_bfloat16* __restrict__ WhTb = WhT + (size_t)b * 256 * 2048;
#pragma unroll
  for (int qt = 0; qt < 4; ++qt)
#pragma unroll
    for (int ot = 0; ot < 4; ++ot) {
      const int o = wid * 64 + ot * 16 + (lane & 15);
      const int ql = q0 + qt * 16 + ((lane >> 4) << 2);
      u32x2 pk;
      pk[0] = (unsigned)f2bf(acc[qt][ot][0]) | ((unsigned)f2bf(acc[qt][ot][1]) << 16);
      pk[1] = (unsigned)f2bf(acc[qt][ot][2]) | ((unsigned)f2bf(acc[qt][ot][3]) << 16);
      *(u32x2*)&WhTb[(size_t)o * 2048 + ql] = pk;
    }
}

// ---------------------------------------------------------------------------
// Kernel B: fused masked-softmax + PV. Fixed per-row bound m_p (no rescale).
// r3 structure (LDS-staged Bs, dbuf, one lgkm-drain barrier per 64-q tile)
// + depth-2 register ring for adj/s (issue at tile i for tile i+2) and
// issue-order discipline: breg (L2-fast) issued before adj (HBM-slow) so
// counted vmcnt waits on breg never drain the adj stream. setprio on MFMA.
// ---------------------------------------------------------------------------
__global__ __launch_bounds__(512, 4) void gat_attn(
    const int* __restrict__ adj, const float* __restrict__ s,
    const __hip_bfloat16* __restrict__ WhT, float* __restrict__ out)
{
  const int N = 2048;
  const int bid = blockIdx.x;
  const int swz = (bid & 7) * 64 + (bid >> 3);   // XCD-major: batch == XCD
  const int b = swz >> 6;
  const int p0 = (swz & 63) * 32;
  const int t = threadIdx.x;
  const int wid = t >> 6, lane = t & 63;

  __shared__ __align__(16) unsigned char Bs[2][256 * 128]; // WhT tile dbuf
  __shared__ __align__(16) unsigned char Wt[2][32 * 128];  // P tile dbuf
  __shared__ __align__(16) float red_sh[8];
  __shared__ __align__(16) float l_sh[32];

  const int ep = t >> 4;              // p-row 0..31 (16 thr/row)
  const int eq4 = (t & 15) * 4;       // 4 q per thread
  const int* __restrict__ adjrow = adj + ((size_t)(b * N + p0 + ep)) * N;
  const float* __restrict__ sB = s + b * N;
  const __hip_bfloat16* __restrict__ WhTb = WhT + (size_t)b * 256 * 2048;

  const int so = t >> 3;              // Bs staging o-base 0..63
  const int q16 = t & 7;              // 16B chunk in 128B row

  // ---- block-wide smax over s[b,:] (fixed softmax bound) ----
  const f32x4 s4 = *(const f32x4*)&sB[t * 4];
  float bm = fmaxf(fmaxf(s4[0], s4[1]), fmaxf(s4[2], s4[3]));
#pragma unroll
  for (int off = 1; off < 64; off <<= 1) bm = fmaxf(bm, __shfl_xor(bm, off, 64));
  if (lane == 0) red_sh[wid] = bm;
  const float s_p = sB[p0 + ep];
  __syncthreads();
  float smax = red_sh[0];
#pragma unroll
  for (int k = 1; k < 8; ++k) smax = fmaxf(smax, red_sh[k]);
  const float xm = s_p + smax;
  const float m_p = (xm > 0.f) ? xm : (LEAKY_ALPHA * xm);

  f32x4 acc[2][2];
#pragma unroll
  for (int pt = 0; pt < 2; ++pt)
#pragma unroll
    for (int ot = 0; ot < 2; ++ot) acc[pt][ot] = (f32x4)(0.f);
  float lacc = 0.f;

  // ---- prologue: breg(tile0) first (fast stream), then adj/s ring ----
  u32x4 breg[4];
#pragma unroll
  for (int j = 0; j < 4; ++j)
    breg[j] = *(const u32x4*)&WhTb[(size_t)(so + 64 * j) * 2048 + q16 * 8];

  i32x4 aE = *(const i32x4*)&adjrow[eq4];           // tile 0 (even slot)
  f32x4 sE = *(const f32x4*)&sB[eq4];
  i32x4 aO = *(const i32x4*)&adjrow[64 + eq4];      // tile 1 (odd slot)
  f32x4 sO = *(const f32x4*)&sB[64 + eq4];

  const int wtoff = ep * 128 + ((eq4 * 2) ^ ((ep & 7) << 4));

  // Per tile: BI = LDS buffer, QQ = q base; AV/SV = this tile's ring slot,
  // refilled for QQ+128 (2 tiles ahead).
  auto tile = [&](int BI, int QQ, i32x4& AV, f32x4& SV) __attribute__((always_inline)) {
    // scores from ring regs (arrived >=2 phases ago)
    float wv[4];
#pragma unroll
    for (int i = 0; i < 4; ++i) {
      const float x = s_p + SV[i];
      const float le = (x > 0.f) ? x : (LEAKY_ALPHA * x);
      const float w = __expf(le - m_p);
      wv[i] = (AV[i] != 0) ? w : 0.f;
      lacc += wv[i];
    }
    {
      u32x2 pw;
      pw[0] = (unsigned)f2bf(wv[0]) | ((unsigned)f2bf(wv[1]) << 16);
      pw[1] = (unsigned)f2bf(wv[2]) | ((unsigned)f2bf(wv[3]) << 16);
      *(u32x2*)&Wt[BI][wtoff] = pw;
    }
    // write Bs (waits counted-vmcnt for breg only; adj issued after it)
#pragma unroll
    for (int j = 0; j < 4; ++j) {
      const int o = so + 64 * j;
      *(u32x4*)&Bs[BI][o * 128 + ((q16 * 16) ^ ((o & 7) << 4))] = breg[j];
    }
    // issue next tile's breg (L2-fast) FIRST...
    if (QQ + 64 < N) {
#pragma unroll
      for (int j = 0; j < 4; ++j)
        breg[j] = *(const u32x4*)&WhTb[(size_t)(so + 64 * j) * 2048 +
                                       QQ + 64 + q16 * 8];
    }
    // ...then refill this ring slot for QQ+128 (HBM-slow adj last)
    if (QQ + 128 < N) {
      AV = *(const i32x4*)&adjrow[QQ + 128 + eq4];
      SV = *(const f32x4*)&sB[QQ + 128 + eq4];
    }
    asm volatile("s_waitcnt lgkmcnt(0)" ::: "memory");
    __builtin_amdgcn_s_barrier();
    asm volatile("" ::: "memory");
    {
      s16x8 afr[2][2], bfr[2][2];
#pragma unroll
      for (int pt = 0; pt < 2; ++pt)
#pragma unroll
        for (int kt = 0; kt < 2; ++kt) {
          const int pa = pt * 16 + (lane & 15);
          const int kb = kt * 64 + ((lane >> 4) << 4);
          afr[pt][kt] = *(const s16x8*)&Wt[BI][pa * 128 + (kb ^ ((pa & 7) << 4))];
        }
#pragma unroll
      for (int ot = 0; ot < 2; ++ot)
#pragma unroll
        for (int kt = 0; kt < 2; ++kt) {
          const int ob = wid * 32 + ot * 16 + (lane & 15);
          const int kb = kt * 64 + ((lane >> 4) << 4);
          bfr[ot][kt] = *(const s16x8*)&Bs[BI][ob * 128 + (kb ^ ((ob & 7) << 4))];
        }
      __builtin_amdgcn_s_setprio(1);
#pragma unroll
      for (int pt = 0; pt < 2; ++pt)
#pragma unroll
        for (int ot = 0; ot < 2; ++ot)
#pragma unroll
          for (int kt = 0; kt < 2; ++kt)
            acc[pt][ot] = __builtin_amdgcn_mfma_f32_16x16x32_bf16(
                afr[pt][kt], bfr[ot][kt], acc[pt][ot], 0, 0, 0);
      __builtin_amdgcn_s_setprio(0);
    }
  };

  for (int q0 = 0; q0 < N; q0 += 128) {
    tile(0, q0, aE, sE);
    tile(1, q0 + 64, aO, sO);
  }

  // ---- l reduction: 16 threads per row -> l_sh ----
  lacc += __shfl_xor(lacc, 1, 64);
  lacc += __shfl_xor(lacc, 2, 64);
  lacc += __shfl_xor(lacc, 4, 64);
  lacc += __shfl_xor(lacc, 8, 64);
  if ((t & 15) == 0) l_sh[ep] = lacc;
  __syncthreads();

  // ---- epilogue: divide by l, store fp32 ----
#pragma unroll
  for (int pt = 0; pt < 2; ++pt) {
    const f32x4 lv = *(const f32x4*)&l_sh[pt * 16 + ((lane >> 4) << 2)];
    f32x4 inv;
#pragma unroll
    for (int r = 0; r < 4; ++r) inv[r] = 1.f / lv[r];
#pragma unroll
    for (int ot = 0; ot < 2; ++ot) {
      const int o = wid * 32 + ot * 16 + (lane & 15);
#pragma unroll
      for (int r = 0; r < 4; ++r) {
        const int row = p0 + pt * 16 + ((lane >> 4) << 2) + r;
        out[((size_t)(b * N + row)) * 256 + o] = acc[pt][ot][r] * inv[r];
      }
    }
  }
}

extern "C" void kernel_launch(void* const* d_in, const int* in_sizes, int n_in,
                              void* d_out, int out_size, void* d_ws, size_t ws_size,
                              hipStream_t stream) {
  const float* h = (const float*)d_in[0];
  const int* adj = (const int*)d_in[1];
  const float* W = (const float*)d_in[2];
  float* out = (float*)d_out;

  char* ws = (char*)d_ws;
  __hip_bfloat16* WhT = (__hip_bfloat16*)ws;                              // 8 MiB
  float* s = (float*)(ws + (size_t)8 * 1024 * 1024);                      // 64 KiB
  __hip_bfloat16* WT = (__hip_bfloat16*)(ws + (size_t)8 * 1024 * 1024 + 65536);   // 128 KiB
  float* wsum = (float*)(ws + (size_t)8 * 1024 * 1024 + 65536 + 131072);  // 1 KiB

  gat_prep<<<256, 256, 0, stream>>>(W, WT, wsum);
  gat_wh2<<<256, 256, 0, stream>>>(h, WT, wsum, WhT, s);
  gat_attn<<<512, 512, 0, stream>>>(adj, s, WhT, out);
}